// Round 9
// baseline (710.688 us; speedup 1.0000x reference)
//
#include <hip/hip_runtime.h>

#define NN 2048
#define KK 20
#define BB 16
#define TPRE 1.79989f   // relu(A) prefilter; key>=1.8 => v>=1.8-1e-4 (noise<1)
#define CAP 128         // candidate capacity per wave (mean ~74, 6.4 sigma)

typedef __attribute__((ext_vector_type(4))) float f32x4;

// ---------------------------------------------------------------------------
// Kernel 1 (v10): per-row exact top-K. One wave per row.
// Compaction rewritten: the 32-step serial ballot->popc->add chain (~1000cy
// on the wave critical path, dominant VALU cost) is replaced by
//   per-lane count (32 parallel adds) -> 6-step shfl_up wave scan ->
//   each lane writes its OWN candidates, gathering its OWN noise inline.
// Storage order in LDS is unordered-across-lanes — irrelevant, because
// selection is rank-based on packed u64 keys:
//   packed = (float_bits(key) << 32) | (NN-1-idx)   (key>0 => bits monotonic)
//   rank(x) = #{y : packed_y > packed_x};  selected iff rank < K; slot = rank
// (exact lax.top_k semantics incl. low-index tie preference; emission order
// is irrelevant downstream — the reference builds a 0/1 mask.)
// Slim EMIT (scatter output path): sel stores + fire-and-forget colsum atomic.
// Fallback only for cnt<K or cnt>CAP (P ~ 1e-10/row): full-row re-read
// bisection + tie handling (independent of LDS state).
// ---------------------------------------------------------------------------
__global__ __launch_bounds__(256) void topk_kernel(
    const float* __restrict__ A, const float* __restrict__ noise,
    int* __restrict__ sel_idx, float* __restrict__ sel_val,
    float* __restrict__ colsum)
{
    __shared__ unsigned long long cand_pk[4][CAP + 8];
    __shared__ float cand_val[4][CAP];
    __shared__ int   tie_idx[4][64];
    __shared__ int   tie_cnt[4];

    const int lane = threadIdx.x & 63;
    const int wv   = threadIdx.x >> 6;
    const int row  = blockIdx.x * 4 + wv;          // 0 .. 32767
    const float* Ar = A     + (size_t)row * NN;
    const float* Nr = noise + (size_t)row * NN;
    const int colbase = row & ~(NN - 1);           // b * N
    const unsigned long long ltm = (1ull << lane) - 1ull;

    int*   si = sel_idx + (size_t)row * KK;
    float* sv = sel_val + (size_t)row * KK;

#define EMIT(POS, IDX, V)                                                      \
    do {                                                                       \
        int _p = (POS); int _i = (IDX); float _v = (V);                        \
        si[_p] = _i; sv[_p] = _v;                                              \
        atomicAdd(&colsum[colbase + _i], _v);                                  \
    } while (0)

    // ---- Load burst: 8 independent dwordx4 loads --------------------------
    float4 a[8];
#pragma unroll
    for (int c = 0; c < 8; ++c)
        a[c] = *(const float4*)(Ar + c * 256 + lane * 4);

    // ---- Pass 1: per-lane candidate count (no cross-lane chain) -----------
    int lc = 0;
#pragma unroll
    for (int c = 0; c < 8; ++c) {
        lc += (fmaxf(a[c].x, 0.f) >= TPRE);
        lc += (fmaxf(a[c].y, 0.f) >= TPRE);
        lc += (fmaxf(a[c].z, 0.f) >= TPRE);
        lc += (fmaxf(a[c].w, 0.f) >= TPRE);
    }

    // ---- Wave scan: 6 shfl_up steps -> per-lane base + wave total ---------
    int inc = lc;
#pragma unroll
    for (int s = 1; s < 64; s <<= 1) {
        int u = __shfl_up(inc, s);
        if (lane >= s) inc += u;
    }
    const int cnt = __shfl(inc, 63);

    bool done = false;
    if (cnt >= KK && cnt <= CAP) {
        // ---- Pass 2: write own candidates, gather own noise inline --------
        int pos = inc - lc;                        // exclusive prefix
#pragma unroll
        for (int c = 0; c < 8; ++c) {
            float av[4] = {a[c].x, a[c].y, a[c].z, a[c].w};
#pragma unroll
            for (int q = 0; q < 4; ++q) {
                float v = fmaxf(av[q], 0.f);
                if (v >= TPRE) {
                    int idx = c * 256 + lane * 4 + q;
                    float k = fmaf(Nr[idx], 1e-4f, v);
                    cand_pk[wv][pos] =
                        ((unsigned long long)__float_as_uint(k) << 32)
                        | (unsigned)(NN - 1 - idx);
                    cand_val[wv][pos] = v;
                    ++pos;
                }
            }
        }
        // sentinel pad to multiple of 8 (0 < any real packed key)
        const int nIter = (cnt + 7) & ~7;
        if (lane < nIter - cnt) cand_pk[wv][cnt + lane] = 0ull;

        // ---- Read back this lane's 2 entries ------------------------------
        unsigned long long pk0 = ~0ull, pk1 = ~0ull;
        float v0 = 0.f, v1 = 0.f;
        if (lane < cnt)      { pk0 = cand_pk[wv][lane];      v0 = cand_val[wv][lane]; }
        if (lane + 64 < cnt) { pk1 = cand_pk[wv][lane + 64]; v1 = cand_val[wv][lane + 64]; }

        // ---- Rank scan: unrolled x8, broadcast b64 reads, pipelined -------
        int r0 = 0, r1 = 0;
        for (int j = 0; j < nIter; j += 8) {
            unsigned long long b[8];
#pragma unroll
            for (int u = 0; u < 8; ++u) b[u] = cand_pk[wv][j + u];
#pragma unroll
            for (int u = 0; u < 8; ++u) {
                r0 += (b[u] > pk0);
                r1 += (b[u] > pk1);
            }
        }
        if (lane < cnt && r0 < KK)
            EMIT(r0, NN - 1 - (int)(pk0 & 0xFFFFFFFFu), v0);
        if (lane + 64 < cnt && r1 < KK)
            EMIT(r1, NN - 1 - (int)(pk1 & 0xFFFFFFFFu), v1);
        done = true;
    }

    if (!done) {
        // ---- Fallback (cold, exact): full-row re-read bisection -----------
        unsigned lo = 0u, hi = 0x7F800000u;
        unsigned tb = 0u;
        bool exact = false;
        while (hi - lo > 1u) {
            unsigned mid = (lo + hi) >> 1;
            float tm = __uint_as_float(mid);
            int c = 0;
            for (int j = 0; j < 32; ++j) {
                float av = Ar[j * 64 + lane];
                float nv = Nr[j * 64 + lane];
                float k = fmaf(nv, 1e-4f, fmaxf(av, 0.f));
                c += __popcll(__ballot(k >= tm));
            }
            if (c == KK) { tb = mid; exact = true; break; }
            if (c > KK) lo = mid; else hi = mid;
        }
        if (exact) {
            float t = __uint_as_float(tb);
            int run = 0;
            for (int j = 0; j < 32; ++j) {
                float av = Ar[j * 64 + lane];
                float nv = Nr[j * 64 + lane];
                float v = fmaxf(av, 0.f);
                float k = fmaf(nv, 1e-4f, v);
                bool p = k >= t;
                unsigned long long m = __ballot(p);
                if (p) EMIT(run + __popcll(m & ltm), j * 64 + lane, v);
                run += __popcll(m);
            }
        } else {
            // Exact tie at the K/K+1 boundary: strictly-greater first, then
            // ascending-index among ties (lax.top_k semantics).
            float t1 = __uint_as_float(lo);
            int run = 0;
            for (int j = 0; j < 32; ++j) {
                float av = Ar[j * 64 + lane];
                float nv = Nr[j * 64 + lane];
                float v = fmaxf(av, 0.f);
                float k = fmaf(nv, 1e-4f, v);
                bool p = k > t1;
                unsigned long long m = __ballot(p);
                if (p) EMIT(run + __popcll(m & ltm), j * 64 + lane, v);
                run += __popcll(m);
            }
            if (lane == 0) tie_cnt[wv] = 0;
            for (int j = 0; j < 32; ++j) {
                float av = Ar[j * 64 + lane];
                float nv = Nr[j * 64 + lane];
                float k = fmaf(nv, 1e-4f, fmaxf(av, 0.f));
                if (k == t1) {
                    int p = atomicAdd(&tie_cnt[wv], 1);
                    if (p < 64) tie_idx[wv][p] = j * 64 + lane;
                }
            }
            if (lane == 0) {
                int n = tie_cnt[wv]; if (n > 64) n = 64;
                int need = KK - run;
                for (int s = 0; s < need; ++s) {
                    int bq = 0, bidx = 0x7fffffff;
                    for (int q = 0; q < n; ++q) {
                        int v = tie_idx[wv][q];
                        if (v < bidx) { bidx = v; bq = q; }
                    }
                    tie_idx[wv][bq] = 0x7fffffff;
                    float v = fmaxf(Ar[bidx], 0.f);
                    EMIT(run + s, bidx, v);
                }
            }
        }
    }
#undef EMIT
}

// ---------------------------------------------------------------------------
// Kernel 2: dinv = (1 + 0.5*(rowsum + colsum))^-1/2.
// ---------------------------------------------------------------------------
__global__ __launch_bounds__(256) void dinv_kernel(
    const float* __restrict__ sel_val, const float* __restrict__ colsum,
    float* __restrict__ dinv)
{
    int r = blockIdx.x * 256 + threadIdx.x;        // 0 .. 32767
    const float* svp = sel_val + (size_t)r * KK;
    float rs = 0.f;
#pragma unroll
    for (int k = 0; k < KK; ++k) rs += svp[k];
    float d = 1.0f + 0.5f * (rs + colsum[r]);
    dinv[r] = 1.0f / sqrtf(d);                     // d >= 1 always
}

// ---------------------------------------------------------------------------
// Kernel 3 (v6 structure — measured best): global scatter onto the
// memset-zeroed output. One thread per (row,k) issues TWO fire-and-forget
// global atomicAdds:
//   out[r][j] += w  and  out[j][r] += w,  w = 0.5*v*d_r*d_j
// plus one thread per row for the diagonal d_r^2. Atomicity exactly handles
// mutual selection and self-loops.
// ---------------------------------------------------------------------------
__global__ __launch_bounds__(256) void scatter_kernel(
    const int* __restrict__ sel_idx, const float* __restrict__ sel_val,
    const float* __restrict__ dinv, float* __restrict__ out)
{
    int tid = blockIdx.x * 256 + threadIdx.x;      // 0 .. 32768*21-1
    int r = tid / 21;                              // magic-mul division
    int s = tid - r * 21;
    const int colbase = r & ~(NN - 1);
    const int i = r & (NN - 1);
    float dr = dinv[r];

    if (s == 20) {
        // (A+I) diagonal term
        atomicAdd(&out[(size_t)r * NN + i], dr * dr);
    } else {
        int   j = sel_idx[(size_t)r * KK + s];
        float v = sel_val[(size_t)r * KK + s];
        float w = 0.5f * v * dr * dinv[colbase + j];
        atomicAdd(&out[(size_t)r * NN + j], w);
        atomicAdd(&out[(size_t)(colbase + j) * NN + i], w);
    }
}

// ---------------------------------------------------------------------------
extern "C" void kernel_launch(void* const* d_in, const int* in_sizes, int n_in,
                              void* d_out, int out_size, void* d_ws, size_t ws_size,
                              hipStream_t stream)
{
    const float* A     = (const float*)d_in[0];
    const float* noise = (const float*)d_in[1];
    float* out = (float*)d_out;
    char*  ws  = (char*)d_ws;

    const int rows = BB * NN;                      // 32768
    // workspace layout (~5.5 MB total)
    size_t off = 0;
    int*   sel_idx = (int*)(ws + off);            off += (size_t)rows * KK * 4;   // 2.62 MB
    float* sel_val = (float*)(ws + off);          off += (size_t)rows * KK * 4;   // 2.62 MB
    float* colsum  = (float*)(ws + off);          off += (size_t)rows * 4;        // 128 KB
    float* dinv    = (float*)(ws + off);                                          // 128 KB

    hipMemsetAsync(out, 0, (size_t)out_size, stream);
    hipMemsetAsync(colsum, 0, rows * sizeof(float), stream);

    topk_kernel<<<rows / 4, 256, 0, stream>>>(A, noise, sel_idx, sel_val, colsum);
    dinv_kernel<<<rows / 256, 256, 0, stream>>>(sel_val, colsum, dinv);
    scatter_kernel<<<rows * 21 / 256, 256, 0, stream>>>(sel_idx, sel_val, dinv, out);
}

// Round 10
// 628.915 us; speedup vs baseline: 1.1300x; 1.1300x over previous
//
#include <hip/hip_runtime.h>

#define NN 2048
#define KK 20
#define BB 16
#define TPRE 1.79989f   // relu(A) prefilter; key>=1.8 => v>=1.8-1e-4 (noise<1)
#define CAP 128         // candidate capacity per wave (mean ~74, 6.4 sigma)

typedef __attribute__((ext_vector_type(4))) float f32x4;

// ---------------------------------------------------------------------------
// Kernel 1 (v11): per-row exact top-K. One wave per row.
// Structure = v6 (measured 165.8us, session-best total 619us): ballot-prefix
// compaction -> noise gather at candidates -> rank-based selection on packed
// u64 keys -> slim EMIT (2 stores + fire-and-forget colsum atomic).
//   packed = (float_bits(key) << 32) | (NN-1-idx)   (key>0 => bits monotonic)
//   rank(x) = #{y : packed_y > packed_x};  selected iff rank < K; slot = rank.
// v11 deltas (occupancy): __launch_bounds__(256,8) caps VGPR at 64 — v6's
// 68 VGPRs fell in the 16-waves/CU class (pool halves crossing 64); <=64
// doubles the ceiling to 32. Rank-scan unroll reduced 8->4 (frees the 16-VGPR
// b[] buffer to 8) so the cap doesn't spill. Kernel is latency-bound
// (1.67 TB/s, VALU 24%): resident waves are the direct lever.
// Fallback only for cnt<K or cnt>CAP (P ~ 1e-10/row): full-row re-read
// bisection + tie handling.
// ---------------------------------------------------------------------------
__global__ __launch_bounds__(256, 8) void topk_kernel(
    const float* __restrict__ A, const float* __restrict__ noise,
    int* __restrict__ sel_idx, float* __restrict__ sel_val,
    float* __restrict__ colsum)
{
    __shared__ unsigned long long cand_pk[4][CAP + 8];
    __shared__ float cand_val[4][CAP];
    __shared__ int   cand_idx[4][CAP];
    __shared__ int   tie_idx[4][64];
    __shared__ int   tie_cnt[4];

    const int lane = threadIdx.x & 63;
    const int wv   = threadIdx.x >> 6;
    const int row  = blockIdx.x * 4 + wv;          // 0 .. 32767
    const float* Ar = A     + (size_t)row * NN;
    const float* Nr = noise + (size_t)row * NN;
    const int colbase = row & ~(NN - 1);           // b * N
    const unsigned long long ltm = (1ull << lane) - 1ull;

    int*   si = sel_idx + (size_t)row * KK;
    float* sv = sel_val + (size_t)row * KK;

#define EMIT(POS, IDX, V)                                                      \
    do {                                                                       \
        int _p = (POS); int _i = (IDX); float _v = (V);                        \
        si[_p] = _i; sv[_p] = _v;                                              \
        atomicAdd(&colsum[colbase + _i], _v);                                  \
    } while (0)

    // ---- Load burst: 8 independent dwordx4 loads --------------------------
    float4 a[8];
#pragma unroll
    for (int c = 0; c < 8; ++c)
        a[c] = *(const float4*)(Ar + c * 256 + lane * 4);

    // ---- Phase 1: ballot-prefix compaction of v-candidates into LDS -------
    int cnt = 0;
#pragma unroll
    for (int c = 0; c < 8; ++c) {
        float av[4] = {a[c].x, a[c].y, a[c].z, a[c].w};
#pragma unroll
        for (int q = 0; q < 4; ++q) {
            float v = fmaxf(av[q], 0.f);
            bool p = v >= TPRE;
            unsigned long long m = __ballot(p);
            if (p) {
                int pos = cnt + __popcll(m & ltm);
                if (pos < CAP) {
                    cand_val[wv][pos] = v;
                    cand_idx[wv][pos] = c * 256 + lane * 4 + q;
                }
            }
            cnt += __popcll(m);
        }
    }

    bool done = false;
    if (cnt >= KK && cnt <= CAP) {
        // ---- Gather noise at candidate positions, pack sortable u64 -------
        int   i0 = (lane      < cnt) ? cand_idx[wv][lane]      : -1;
        int   i1 = (lane + 64 < cnt) ? cand_idx[wv][lane + 64] : -1;
        float v0 = (i0 >= 0) ? cand_val[wv][lane]      : 0.f;
        float v1 = (i1 >= 0) ? cand_val[wv][lane + 64] : 0.f;
        unsigned long long pk0 = ~0ull, pk1 = ~0ull;
        if (i0 >= 0) {
            float k0 = fmaf(Nr[i0], 1e-4f, v0);
            pk0 = ((unsigned long long)__float_as_uint(k0) << 32)
                | (unsigned)(NN - 1 - i0);
            cand_pk[wv][lane] = pk0;
        }
        if (i1 >= 0) {
            float k1 = fmaf(Nr[i1], 1e-4f, v1);
            pk1 = ((unsigned long long)__float_as_uint(k1) << 32)
                | (unsigned)(NN - 1 - i1);
            cand_pk[wv][lane + 64] = pk1;
        }
        // sentinel pad to multiple of 4 (0 < any real packed key)
        int nIter = (cnt + 3) & ~3;
        if (lane < nIter - cnt) cand_pk[wv][cnt + lane] = 0ull;

        // ---- Rank scan: unrolled x4, broadcast b64 reads, pipelined -------
        int r0 = 0, r1 = 0;
        for (int j = 0; j < nIter; j += 4) {
            unsigned long long b[4];
#pragma unroll
            for (int u = 0; u < 4; ++u) b[u] = cand_pk[wv][j + u];
#pragma unroll
            for (int u = 0; u < 4; ++u) {
                r0 += (b[u] > pk0);
                r1 += (b[u] > pk1);
            }
        }
        if (i0 >= 0 && r0 < KK) EMIT(r0, i0, v0);
        if (i1 >= 0 && r1 < KK) EMIT(r1, i1, v1);
        done = true;
    }

    if (!done) {
        // ---- Fallback (cold, exact): full-row re-read bisection -----------
        unsigned lo = 0u, hi = 0x7F800000u;
        unsigned tb = 0u;
        bool exact = false;
        while (hi - lo > 1u) {
            unsigned mid = (lo + hi) >> 1;
            float tm = __uint_as_float(mid);
            int c = 0;
            for (int j = 0; j < 32; ++j) {
                float av = Ar[j * 64 + lane];
                float nv = Nr[j * 64 + lane];
                float k = fmaf(nv, 1e-4f, fmaxf(av, 0.f));
                c += __popcll(__ballot(k >= tm));
            }
            if (c == KK) { tb = mid; exact = true; break; }
            if (c > KK) lo = mid; else hi = mid;
        }
        if (exact) {
            float t = __uint_as_float(tb);
            int run = 0;
            for (int j = 0; j < 32; ++j) {
                float av = Ar[j * 64 + lane];
                float nv = Nr[j * 64 + lane];
                float v = fmaxf(av, 0.f);
                float k = fmaf(nv, 1e-4f, v);
                bool p = k >= t;
                unsigned long long m = __ballot(p);
                if (p) EMIT(run + __popcll(m & ltm), j * 64 + lane, v);
                run += __popcll(m);
            }
        } else {
            // Exact tie at the K/K+1 boundary: strictly-greater first, then
            // ascending-index among ties (lax.top_k semantics).
            float t1 = __uint_as_float(lo);
            int run = 0;
            for (int j = 0; j < 32; ++j) {
                float av = Ar[j * 64 + lane];
                float nv = Nr[j * 64 + lane];
                float v = fmaxf(av, 0.f);
                float k = fmaf(nv, 1e-4f, v);
                bool p = k > t1;
                unsigned long long m = __ballot(p);
                if (p) EMIT(run + __popcll(m & ltm), j * 64 + lane, v);
                run += __popcll(m);
            }
            if (lane == 0) tie_cnt[wv] = 0;
            for (int j = 0; j < 32; ++j) {
                float av = Ar[j * 64 + lane];
                float nv = Nr[j * 64 + lane];
                float k = fmaf(nv, 1e-4f, fmaxf(av, 0.f));
                if (k == t1) {
                    int p = atomicAdd(&tie_cnt[wv], 1);
                    if (p < 64) tie_idx[wv][p] = j * 64 + lane;
                }
            }
            if (lane == 0) {
                int n = tie_cnt[wv]; if (n > 64) n = 64;
                int need = KK - run;
                for (int s = 0; s < need; ++s) {
                    int bq = 0, bidx = 0x7fffffff;
                    for (int q = 0; q < n; ++q) {
                        int v = tie_idx[wv][q];
                        if (v < bidx) { bidx = v; bq = q; }
                    }
                    tie_idx[wv][bq] = 0x7fffffff;
                    float v = fmaxf(Ar[bidx], 0.f);
                    EMIT(run + s, bidx, v);
                }
            }
        }
    }
#undef EMIT
}

// ---------------------------------------------------------------------------
// Kernel 2: dinv = (1 + 0.5*(rowsum + colsum))^-1/2.
// ---------------------------------------------------------------------------
__global__ __launch_bounds__(256) void dinv_kernel(
    const float* __restrict__ sel_val, const float* __restrict__ colsum,
    float* __restrict__ dinv)
{
    int r = blockIdx.x * 256 + threadIdx.x;        // 0 .. 32767
    const float* svp = sel_val + (size_t)r * KK;
    float rs = 0.f;
#pragma unroll
    for (int k = 0; k < KK; ++k) rs += svp[k];
    float d = 1.0f + 0.5f * (rs + colsum[r]);
    dinv[r] = 1.0f / sqrtf(d);                     // d >= 1 always
}

// ---------------------------------------------------------------------------
// Kernel 3 (v6 structure — measured best): global scatter onto the
// memset-zeroed output. One thread per (row,k) issues TWO fire-and-forget
// global atomicAdds:
//   out[r][j] += w  and  out[j][r] += w,  w = 0.5*v*d_r*d_j
// plus one thread per row for the diagonal d_r^2. Atomicity exactly handles
// mutual selection and self-loops.
// ---------------------------------------------------------------------------
__global__ __launch_bounds__(256) void scatter_kernel(
    const int* __restrict__ sel_idx, const float* __restrict__ sel_val,
    const float* __restrict__ dinv, float* __restrict__ out)
{
    int tid = blockIdx.x * 256 + threadIdx.x;      // 0 .. 32768*21-1
    int r = tid / 21;                              // magic-mul division
    int s = tid - r * 21;
    const int colbase = r & ~(NN - 1);
    const int i = r & (NN - 1);
    float dr = dinv[r];

    if (s == 20) {
        // (A+I) diagonal term
        atomicAdd(&out[(size_t)r * NN + i], dr * dr);
    } else {
        int   j = sel_idx[(size_t)r * KK + s];
        float v = sel_val[(size_t)r * KK + s];
        float w = 0.5f * v * dr * dinv[colbase + j];
        atomicAdd(&out[(size_t)r * NN + j], w);
        atomicAdd(&out[(size_t)(colbase + j) * NN + i], w);
    }
}

// ---------------------------------------------------------------------------
extern "C" void kernel_launch(void* const* d_in, const int* in_sizes, int n_in,
                              void* d_out, int out_size, void* d_ws, size_t ws_size,
                              hipStream_t stream)
{
    const float* A     = (const float*)d_in[0];
    const float* noise = (const float*)d_in[1];
    float* out = (float*)d_out;
    char*  ws  = (char*)d_ws;

    const int rows = BB * NN;                      // 32768
    // workspace layout (~5.5 MB total)
    size_t off = 0;
    int*   sel_idx = (int*)(ws + off);            off += (size_t)rows * KK * 4;   // 2.62 MB
    float* sel_val = (float*)(ws + off);          off += (size_t)rows * KK * 4;   // 2.62 MB
    float* colsum  = (float*)(ws + off);          off += (size_t)rows * 4;        // 128 KB
    float* dinv    = (float*)(ws + off);                                          // 128 KB

    hipMemsetAsync(out, 0, (size_t)out_size, stream);
    hipMemsetAsync(colsum, 0, rows * sizeof(float), stream);

    topk_kernel<<<rows / 4, 256, 0, stream>>>(A, noise, sel_idx, sel_val, colsum);
    dinv_kernel<<<rows / 256, 256, 0, stream>>>(sel_val, colsum, dinv);
    scatter_kernel<<<rows * 21 / 256, 256, 0, stream>>>(sel_idx, sel_val, dinv, out);
}

// Round 11
// 586.877 us; speedup vs baseline: 1.2110x; 1.0716x over previous
//
#include <hip/hip_runtime.h>

#define NN 2048
#define KK 20
#define BB 16
#define TPRE 1.79989f   // relu(A) prefilter; key>=1.8 => v>=1.8-1e-4 (noise<1)
#define CAP 128         // candidate capacity per wave (mean ~74, 6.4 sigma)

typedef __attribute__((ext_vector_type(4))) float f32x4;

// ---------------------------------------------------------------------------
// Kernel 1 (v12): per-row exact top-K. One wave per row.
// NEW: noise-free fast path. key = v + noise*1e-4 with noise in [0,1), so
// the perturbation is < 1e-4. If the gap between the K-th and (K+1)-th
// largest v among candidates is >= 1e-4, the top-K SET by key == top-K SET
// by v (x in, y out: key_x >= v_x >= vK = vK1+1e-4 > v_y + n_y*1e-4 = key_y,
// strict since n_y < 1). Downstream consumes only the index SET (mask
// semantics — relied on since v4). Gaussian order-stat gaps at rank 20/2048
// are ~1e-2, so ~99% of rows skip the noise gather entirely (shorter wave
// critical path, ~30MB less scattered FETCH). Gap < 1.01e-4 (margin absorbs
// fp rounding) -> slow path: gather noise, re-rank by full key (exact).
// cnt==K emits all candidates (inherits the 6.3-sigma #{key>=1.8}>=K
// guarantee, same as every prior version).
//   packed = (float_bits(x) << 32) | (NN-1-idx)   (x>0 => bits monotonic)
//   rank(c) = #{y : packed_y > packed_c};  selected iff rank < K; slot=rank.
// Fallback for cnt<K or cnt>CAP (P ~ 1e-10/row): full-row re-read bisection.
// ---------------------------------------------------------------------------
__global__ __launch_bounds__(256, 8) void topk_kernel(
    const float* __restrict__ A, const float* __restrict__ noise,
    int* __restrict__ sel_idx, float* __restrict__ sel_val,
    float* __restrict__ colsum)
{
    __shared__ unsigned long long cand_pk[4][CAP + 8];
    __shared__ float cand_val[4][CAP];
    __shared__ int   cand_idx[4][CAP];
    __shared__ float bnd[4][2];
    __shared__ int   tie_idx[4][64];
    __shared__ int   tie_cnt[4];

    const int lane = threadIdx.x & 63;
    const int wv   = threadIdx.x >> 6;
    const int row  = blockIdx.x * 4 + wv;          // 0 .. 32767
    const float* Ar = A     + (size_t)row * NN;
    const float* Nr = noise + (size_t)row * NN;
    const int colbase = row & ~(NN - 1);           // b * N
    const unsigned long long ltm = (1ull << lane) - 1ull;

    int*   si = sel_idx + (size_t)row * KK;
    float* sv = sel_val + (size_t)row * KK;

#define EMIT(POS, IDX, V)                                                      \
    do {                                                                       \
        int _p = (POS); int _i = (IDX); float _v = (V);                        \
        si[_p] = _i; sv[_p] = _v;                                              \
        atomicAdd(&colsum[colbase + _i], _v);                                  \
    } while (0)

#define PACK(X, IDX)                                                           \
    ((((unsigned long long)__float_as_uint(X)) << 32) |                        \
     (unsigned)(NN - 1 - (IDX)))

    // ---- Load burst: 8 independent dwordx4 loads --------------------------
    float4 a[8];
#pragma unroll
    for (int c = 0; c < 8; ++c)
        a[c] = *(const float4*)(Ar + c * 256 + lane * 4);

    // ---- Phase 1: ballot-prefix compaction of v-candidates into LDS -------
    int cnt = 0;
#pragma unroll
    for (int c = 0; c < 8; ++c) {
        float av[4] = {a[c].x, a[c].y, a[c].z, a[c].w};
#pragma unroll
        for (int q = 0; q < 4; ++q) {
            float v = fmaxf(av[q], 0.f);
            bool p = v >= TPRE;
            unsigned long long m = __ballot(p);
            if (p) {
                int pos = cnt + __popcll(m & ltm);
                if (pos < CAP) {
                    cand_val[wv][pos] = v;
                    cand_idx[wv][pos] = c * 256 + lane * 4 + q;
                }
            }
            cnt += __popcll(m);
        }
    }

    bool done = false;
    if (cnt >= KK && cnt <= CAP) {
        int   i0 = (lane      < cnt) ? cand_idx[wv][lane]      : -1;
        int   i1 = (lane + 64 < cnt) ? cand_idx[wv][lane + 64] : -1;
        float v0 = (i0 >= 0) ? cand_val[wv][lane]      : 0.f;
        float v1 = (i1 >= 0) ? cand_val[wv][lane + 64] : 0.f;

        const int nIter = (cnt + 3) & ~3;

        auto rankscan = [&](unsigned long long p0, unsigned long long p1,
                            int& r0, int& r1) {
            r0 = 0; r1 = 0;
            for (int j = 0; j < nIter; j += 4) {
                unsigned long long b[4];
#pragma unroll
                for (int u = 0; u < 4; ++u) b[u] = cand_pk[wv][j + u];
#pragma unroll
                for (int u = 0; u < 4; ++u) {
                    r0 += (b[u] > p0);
                    r1 += (b[u] > p1);
                }
            }
        };

        // ---- Pass A: rank by packed (v, idx) — NO noise reads -------------
        unsigned long long pk0 = ~0ull, pk1 = ~0ull;
        if (i0 >= 0) { pk0 = PACK(v0, i0); cand_pk[wv][lane]      = pk0; }
        if (i1 >= 0) { pk1 = PACK(v1, i1); cand_pk[wv][lane + 64] = pk1; }
        // sentinel pad to multiple of 4 (0 < any real packed key; valid for
        // both passes — pads stay 0)
        if (lane < nIter - cnt) cand_pk[wv][cnt + lane] = 0ull;

        int r0, r1;
        rankscan(pk0, pk1, r0, r1);

        // boundary values vK (rank K-1) and vK1 (rank K); ranks are unique
        if (i0 >= 0) {
            if (r0 == KK - 1) bnd[wv][0] = v0;
            if (r0 == KK)     bnd[wv][1] = v0;
        }
        if (i1 >= 0) {
            if (r1 == KK - 1) bnd[wv][0] = v1;
            if (r1 == KK)     bnd[wv][1] = v1;
        }

        // wave-uniform gap test (cnt==K: all candidates emitted, no bnd read)
        bool gapok = (cnt == KK) || (bnd[wv][0] - bnd[wv][1] > 1.01e-4f);

        if (!gapok) {
            // ---- Pass B (rare ~1%): gather noise, re-rank by full key -----
            if (i0 >= 0) {
                float k0 = fmaf(Nr[i0], 1e-4f, v0);
                pk0 = PACK(k0, i0); cand_pk[wv][lane] = pk0;
            }
            if (i1 >= 0) {
                float k1 = fmaf(Nr[i1], 1e-4f, v1);
                pk1 = PACK(k1, i1); cand_pk[wv][lane + 64] = pk1;
            }
            rankscan(pk0, pk1, r0, r1);
        }

        if (i0 >= 0 && r0 < KK) EMIT(r0, i0, v0);
        if (i1 >= 0 && r1 < KK) EMIT(r1, i1, v1);
        done = true;
    }

    if (!done) {
        // ---- Fallback (cold, exact): full-row re-read bisection -----------
        unsigned lo = 0u, hi = 0x7F800000u;
        unsigned tb = 0u;
        bool exact = false;
        while (hi - lo > 1u) {
            unsigned mid = (lo + hi) >> 1;
            float tm = __uint_as_float(mid);
            int c = 0;
            for (int j = 0; j < 32; ++j) {
                float av = Ar[j * 64 + lane];
                float nv = Nr[j * 64 + lane];
                float k = fmaf(nv, 1e-4f, fmaxf(av, 0.f));
                c += __popcll(__ballot(k >= tm));
            }
            if (c == KK) { tb = mid; exact = true; break; }
            if (c > KK) lo = mid; else hi = mid;
        }
        if (exact) {
            float t = __uint_as_float(tb);
            int run = 0;
            for (int j = 0; j < 32; ++j) {
                float av = Ar[j * 64 + lane];
                float nv = Nr[j * 64 + lane];
                float v = fmaxf(av, 0.f);
                float k = fmaf(nv, 1e-4f, v);
                bool p = k >= t;
                unsigned long long m = __ballot(p);
                if (p) EMIT(run + __popcll(m & ltm), j * 64 + lane, v);
                run += __popcll(m);
            }
        } else {
            // Exact tie at the K/K+1 boundary: strictly-greater first, then
            // ascending-index among ties (lax.top_k semantics).
            float t1 = __uint_as_float(lo);
            int run = 0;
            for (int j = 0; j < 32; ++j) {
                float av = Ar[j * 64 + lane];
                float nv = Nr[j * 64 + lane];
                float v = fmaxf(av, 0.f);
                float k = fmaf(nv, 1e-4f, v);
                bool p = k > t1;
                unsigned long long m = __ballot(p);
                if (p) EMIT(run + __popcll(m & ltm), j * 64 + lane, v);
                run += __popcll(m);
            }
            if (lane == 0) tie_cnt[wv] = 0;
            for (int j = 0; j < 32; ++j) {
                float av = Ar[j * 64 + lane];
                float nv = Nr[j * 64 + lane];
                float k = fmaf(nv, 1e-4f, fmaxf(av, 0.f));
                if (k == t1) {
                    int p = atomicAdd(&tie_cnt[wv], 1);
                    if (p < 64) tie_idx[wv][p] = j * 64 + lane;
                }
            }
            if (lane == 0) {
                int n = tie_cnt[wv]; if (n > 64) n = 64;
                int need = KK - run;
                for (int s = 0; s < need; ++s) {
                    int bq = 0, bidx = 0x7fffffff;
                    for (int q = 0; q < n; ++q) {
                        int v = tie_idx[wv][q];
                        if (v < bidx) { bidx = v; bq = q; }
                    }
                    tie_idx[wv][bq] = 0x7fffffff;
                    float v = fmaxf(Ar[bidx], 0.f);
                    EMIT(run + s, bidx, v);
                }
            }
        }
    }
#undef EMIT
#undef PACK
}

// ---------------------------------------------------------------------------
// Kernel 2: dinv = (1 + 0.5*(rowsum + colsum))^-1/2.
// ---------------------------------------------------------------------------
__global__ __launch_bounds__(256) void dinv_kernel(
    const float* __restrict__ sel_val, const float* __restrict__ colsum,
    float* __restrict__ dinv)
{
    int r = blockIdx.x * 256 + threadIdx.x;        // 0 .. 32767
    const float* svp = sel_val + (size_t)r * KK;
    float rs = 0.f;
#pragma unroll
    for (int k = 0; k < KK; ++k) rs += svp[k];
    float d = 1.0f + 0.5f * (rs + colsum[r]);
    dinv[r] = 1.0f / sqrtf(d);                     // d >= 1 always
}

// ---------------------------------------------------------------------------
// Kernel 3 (v6 structure — measured best): global scatter onto the
// memset-zeroed output. One thread per (row,k) issues TWO fire-and-forget
// global atomicAdds:
//   out[r][j] += w  and  out[j][r] += w,  w = 0.5*v*d_r*d_j
// plus one thread per row for the diagonal d_r^2. Atomicity exactly handles
// mutual selection and self-loops.
// ---------------------------------------------------------------------------
__global__ __launch_bounds__(256) void scatter_kernel(
    const int* __restrict__ sel_idx, const float* __restrict__ sel_val,
    const float* __restrict__ dinv, float* __restrict__ out)
{
    int tid = blockIdx.x * 256 + threadIdx.x;      // 0 .. 32768*21-1
    int r = tid / 21;                              // magic-mul division
    int s = tid - r * 21;
    const int colbase = r & ~(NN - 1);
    const int i = r & (NN - 1);
    float dr = dinv[r];

    if (s == 20) {
        // (A+I) diagonal term
        atomicAdd(&out[(size_t)r * NN + i], dr * dr);
    } else {
        int   j = sel_idx[(size_t)r * KK + s];
        float v = sel_val[(size_t)r * KK + s];
        float w = 0.5f * v * dr * dinv[colbase + j];
        atomicAdd(&out[(size_t)r * NN + j], w);
        atomicAdd(&out[(size_t)(colbase + j) * NN + i], w);
    }
}

// ---------------------------------------------------------------------------
extern "C" void kernel_launch(void* const* d_in, const int* in_sizes, int n_in,
                              void* d_out, int out_size, void* d_ws, size_t ws_size,
                              hipStream_t stream)
{
    const float* A     = (const float*)d_in[0];
    const float* noise = (const float*)d_in[1];
    float* out = (float*)d_out;
    char*  ws  = (char*)d_ws;

    const int rows = BB * NN;                      // 32768
    // workspace layout (~5.5 MB total)
    size_t off = 0;
    int*   sel_idx = (int*)(ws + off);            off += (size_t)rows * KK * 4;   // 2.62 MB
    float* sel_val = (float*)(ws + off);          off += (size_t)rows * KK * 4;   // 2.62 MB
    float* colsum  = (float*)(ws + off);          off += (size_t)rows * 4;        // 128 KB
    float* dinv    = (float*)(ws + off);                                          // 128 KB

    hipMemsetAsync(out, 0, (size_t)out_size, stream);
    hipMemsetAsync(colsum, 0, rows * sizeof(float), stream);

    topk_kernel<<<rows / 4, 256, 0, stream>>>(A, noise, sel_idx, sel_val, colsum);
    dinv_kernel<<<rows / 256, 256, 0, stream>>>(sel_val, colsum, dinv);
    scatter_kernel<<<rows * 21 / 256, 256, 0, stream>>>(sel_idx, sel_val, dinv, out);
}